// Round 6
// baseline (2080.498 us; speedup 1.0000x reference)
//
#include <hip/hip_runtime.h>

#define B_ 4
#define C_ 128
#define L_ 128
#define N_ 64

__device__ __forceinline__ float fget(const float4& v, int e) {
    switch (e) { case 0: return v.x; case 1: return v.y; case 2: return v.z; default: return v.w; }
}

__device__ __forceinline__ void cfma(float4& ar, float4& ai, float kr, float ki,
                                     const float4& vr, const float4& vi) {
    ar.x += kr * vr.x - ki * vi.x; ai.x += kr * vi.x + ki * vr.x;
    ar.y += kr * vr.y - ki * vi.y; ai.y += kr * vi.y + ki * vr.y;
    ar.z += kr * vr.z - ki * vi.z; ai.z += kr * vi.z + ki * vr.z;
    ar.w += kr * vr.w - ki * vi.w; ai.w += kr * vi.w + ki * vr.w;
}

// real-part complex FMA: acc += wr*zr - wi*zi (componentwise on float4)
#define CFMA4(acc, wr_, wi_, zr_, zi_)                                     \
    acc.x += (wr_) * (zr_).x - (wi_) * (zi_).x;                            \
    acc.y += (wr_) * (zr_).y - (wi_) * (zi_).y;                            \
    acc.z += (wr_) * (zr_).z - (wi_) * (zi_).z;                            \
    acc.w += (wr_) * (zr_).w - (wi_) * (zi_).w;

// ---------------- Kernel A: SSM kernels k0,k1 ----------------
// kbuf floats: [k0_re 16384][k0_im 16384][k1_re 16384][k1_im 16384]
__global__ __launch_bounds__(256) void compute_k_kernel(
    const float* __restrict__ logA, const float* __restrict__ Aim,
    const float* __restrict__ Bre, const float* __restrict__ Bim,
    const float* __restrict__ Cre, const float* __restrict__ Cim,
    const float* __restrict__ logdt, float* __restrict__ kbuf)
{
    int idx = blockIdx.x * 256 + threadIdx.x;   // axis*16384 + c*128 + t
    int axis = idx >> 14;
    int c = (idx >> 7) & 127;
    int t = idx & 127;
    float dt = expf(logdt[axis * C_ + c]);
    float tf = (float)t;
    const float* lA = logA + (axis * C_ + c) * N_;
    const float* br = Bre + (axis * C_ + c) * N_;
    const float* bi = Bim + (axis * C_ + c) * N_;
    const float* cr = Cre + (axis * C_ + c) * N_;
    const float* ci = Cim + (axis * C_ + c) * N_;
    const float* ai = Aim + axis * N_;
    float kr = 0.f, ki = 0.f;
    for (int n = 0; n < N_; ++n) {
        float zre = -expf(lA[n]) * dt;
        float zim = ai[n] * dt;
        float mag = expf(zre * tf);
        float s, co;
        sincosf(zim * tf, &s, &co);
        float wr = mag * co, wi = mag * s;
        float cbr = cr[n] * br[n] - ci[n] * bi[n];
        float cbi = cr[n] * bi[n] + ci[n] * br[n];
        kr += cbr * wr - cbi * wi;
        ki += cbr * wi + cbi * wr;
    }
    kbuf[axis * 32768 + c * L_ + t] = kr;
    kbuf[axis * 32768 + 16384 + c * L_ + t] = ki;
}

// ---------------- conv_x: z1(x,y) = sum_{a<=x} k0[x-a]*u(a,y) ----------------
__global__ __launch_bounds__(512) void conv_x_kernel(
    const float* __restrict__ u_re, const float* __restrict__ u_im,
    const float* __restrict__ kbuf, float* __restrict__ z_re, float* __restrict__ z_im)
{
    __shared__ float sre[128 * 64];
    __shared__ float sim[128 * 64];
    __shared__ float ktr[136], kti[136];
    int blk = blockIdx.x;
    int half = blk & 1;
    int c = (blk >> 1) & 127;
    int b = blk >> 8;
    int tid = threadIdx.x;
    if (tid < 136) {
        int t = tid - 7;
        bool v = (t >= 0) && (t < 128);
        ktr[tid] = v ? kbuf[c * 128 + t] : 0.f;
        kti[tid] = v ? kbuf[16384 + c * 128 + t] : 0.f;
    }
    size_t base = (size_t)(b * 128 + c) * 16384;
#pragma unroll
    for (int it = 0; it < 4; ++it) {
        int i4 = it * 512 + tid;
        int r = i4 >> 4, c4 = i4 & 15;
        float4 vr = *(const float4*)(u_re + base + r * 128 + half * 64 + 4 * c4);
        float4 vi = *(const float4*)(u_im + base + r * 128 + half * 64 + 4 * c4);
        int p = r * 64 + 4 * (c4 ^ (r & 15));
        *(float4*)&sre[p] = vr;
        *(float4*)&sim[p] = vi;
    }
    __syncthreads();
    int w = tid >> 6;
    int wb = half ? (7 - w) : w;            // parity flip: co-resident blocks complement
    int lane = tid & 63;
    int rq = 4 * wb + ((lane >> 4) & 3);    // output x-block 0..31
    int cq = lane & 15;                     // y float4-col
    int r0 = 4 * rq;
    int abound = 16 * wb + 15;              // wave-uniform triangular bound
    float4 accr[4], acci[4];
#pragma unroll
    for (int k = 0; k < 4; ++k) {
        accr[k] = make_float4(0.f, 0.f, 0.f, 0.f);
        acci[k] = make_float4(0.f, 0.f, 0.f, 0.f);
    }
    for (int a = 0; a <= abound; ++a) {
        int p = a * 64 + 4 * (cq ^ (a & 15));
        float4 vr = *(const float4*)&sre[p];
        float4 vi = *(const float4*)&sim[p];
        int jb = r0 - a + 7;
#pragma unroll
        for (int k = 0; k < 4; ++k) {
            int j = jb + k; j = j < 0 ? 0 : j;
            cfma(accr[k], acci[k], ktr[j], kti[j], vr, vi);
        }
    }
#pragma unroll
    for (int k = 0; k < 4; ++k) {
        *(float4*)(z_re + base + (size_t)(r0 + k) * 128 + half * 64 + 4 * cq) = accr[k];
        *(float4*)(z_im + base + (size_t)(r0 + k) * 128 + half * 64 + 4 * cq) = acci[k];
    }
}

// ---------------- conv_y: z2(x,y) = sum_{j<=y} k1[y-j]*z1(x,j) ----------------
__global__ __launch_bounds__(512) void conv_y_kernel(
    float* __restrict__ z_re /* ws: z1_re in, z2_im out */,
    float* __restrict__ z_im /* d_out: z1_im in, z2_re out */,
    const float* __restrict__ kbuf)
{
    __shared__ float sre[128 * 64];
    __shared__ float sim[128 * 64];
    __shared__ float ktr[136], kti[136];
    int blk = blockIdx.x;
    int half = blk & 1;
    int c = (blk >> 1) & 127;
    int b = blk >> 8;
    int tid = threadIdx.x;
    if (tid < 136) {
        int t = tid - 7;
        bool v = (t >= 0) && (t < 128);
        ktr[tid] = v ? kbuf[32768 + c * 128 + t] : 0.f;
        kti[tid] = v ? kbuf[49152 + c * 128 + t] : 0.f;
    }
    size_t base = (size_t)(b * 128 + c) * 16384;
#pragma unroll
    for (int it = 0; it < 4; ++it) {
        int i4 = it * 512 + tid;
        int xl = i4 >> 5, q = i4 & 31;
        float4 vr = *(const float4*)(z_re + base + (size_t)(half * 64 + xl) * 128 + 4 * q);
        float4 vi = *(const float4*)(z_im + base + (size_t)(half * 64 + xl) * 128 + 4 * q);
        int c4 = xl >> 2, e0 = xl & 3;
#pragma unroll
        for (int e = 0; e < 4; ++e) {
            int y = 4 * q + e;
            int p = y * 64 + 4 * (c4 ^ (y & 15)) + e0;
            sre[p] = fget(vr, e);
            sim[p] = fget(vi, e);
        }
    }
    __syncthreads();
    int w = tid >> 6;
    int wb = half ? (7 - w) : w;
    int lane = tid & 63;
    int rq = 4 * wb + ((lane >> 4) & 3);    // output y-block 0..31
    int cq = lane & 15;                     // x float4-col
    int r0 = 4 * rq;
    int abound = 16 * wb + 15;
    float4 accr[4], acci[4];
#pragma unroll
    for (int k = 0; k < 4; ++k) {
        accr[k] = make_float4(0.f, 0.f, 0.f, 0.f);
        acci[k] = make_float4(0.f, 0.f, 0.f, 0.f);
    }
    for (int a = 0; a <= abound; ++a) {      // a = j
        int p = a * 64 + 4 * (cq ^ (a & 15));
        float4 vr = *(const float4*)&sre[p];
        float4 vi = *(const float4*)&sim[p];
        int jb = r0 - a + 7;
#pragma unroll
        for (int k = 0; k < 4; ++k) {
            int j = jb + k; j = j < 0 ? 0 : j;
            cfma(accr[k], acci[k], ktr[j], kti[j], vr, vi);
        }
    }
    __syncthreads();
#pragma unroll
    for (int e = 0; e < 4; ++e) {
        int cc = 4 * cq + e;
        int p = cc * 128 + 4 * (rq ^ (cc >> 2));
        *(float4*)&sre[p] = make_float4(fget(accr[0], e), fget(accr[1], e), fget(accr[2], e), fget(accr[3], e));
        *(float4*)&sim[p] = make_float4(fget(acci[0], e), fget(acci[1], e), fget(acci[2], e), fget(acci[3], e));
    }
    __syncthreads();
    int cc = tid >> 3, fq = tid & 7;
#pragma unroll
    for (int mm = 0; mm < 4; ++mm) {
        int o4 = fq + 8 * mm;
        int p = cc * 128 + 4 * (o4 ^ (cc >> 2));
        float4 vre = *(float4*)&sre[p];   // z2_re
        float4 vim = *(float4*)&sim[p];   // z2_im
        *(float4*)(z_im + base + (size_t)(half * 64 + cc) * 128 + 4 * o4) = vre;  // -> d_out
        *(float4*)(z_re + base + (size_t)(half * 64 + cc) * 128 + 4 * o4) = vim;  // -> ws
    }
}

// ---------------- mix v6: out[b,d,s] = sum_c Wre[d,c]*zre[b,c,s] - Wim[d,c]*zim[b,c,s] ----------------
// 512 threads, per-thread 4d x 8s. Spill-proof: named float4 accs, no local arrays.
// Block (b, 128-s tile). In-place on d_out (all reads of own tile complete before writes).
__global__ __launch_bounds__(512, 4) void mix_kernel(
    float* __restrict__ zre /* d_out */, const float* __restrict__ zim /* ws */,
    const float* __restrict__ Wre, const float* __restrict__ Wim)
{
    __shared__ float zr_s[16][128];
    __shared__ float zi_s[16][128];
    __shared__ float wr_s[16][132];
    __shared__ float wi_s[16][132];
    int bid = blockIdx.x;
    int b = bid >> 7, x = bid & 127;
    int tid = threadIdx.x;
    int sq = tid & 15;           // s-octet: s = 8sq .. 8sq+7
    int dq = tid >> 4;           // d-quad:  d = 4dq .. 4dq+3
    float4 a00 = {0,0,0,0}, a01 = {0,0,0,0};   // d0: s-quads 0,1
    float4 a10 = {0,0,0,0}, a11 = {0,0,0,0};
    float4 a20 = {0,0,0,0}, a21 = {0,0,0,0};
    float4 a30 = {0,0,0,0}, a31 = {0,0,0,0};

    for (int c0 = 0; c0 < 128; c0 += 16) {
        __syncthreads();
        {   // z stage: one float4 per thread per array (16 c-rows x 32 quads)
            int cc = tid >> 5, q = tid & 31;
            size_t g = (size_t)(b * 128 + c0 + cc) * 16384 + x * 128 + 4 * q;
            *(float4*)&zr_s[cc][4 * q] = *(const float4*)(zre + g);
            *(float4*)&zi_s[cc][4 * q] = *(const float4*)(zim + g);
        }
        {   // W stage transposed: thread (dW, qc) loads W[dW][c0+4qc..+3] -> w_s[cc][dW]
            int dW = tid >> 2, qc = tid & 3;
            float4 wr4 = *(const float4*)&Wre[dW * 128 + c0 + 4 * qc];
            float4 wi4 = *(const float4*)&Wim[dW * 128 + c0 + 4 * qc];
            wr_s[4 * qc + 0][dW] = wr4.x; wr_s[4 * qc + 1][dW] = wr4.y;
            wr_s[4 * qc + 2][dW] = wr4.z; wr_s[4 * qc + 3][dW] = wr4.w;
            wi_s[4 * qc + 0][dW] = wi4.x; wi_s[4 * qc + 1][dW] = wi4.y;
            wi_s[4 * qc + 2][dW] = wi4.z; wi_s[4 * qc + 3][dW] = wi4.w;
        }
        __syncthreads();
#pragma unroll
        for (int cc = 0; cc < 16; ++cc) {
            float4 w_r = *(float4*)&wr_s[cc][4 * dq];
            float4 w_i = *(float4*)&wi_s[cc][4 * dq];
            float4 zr0 = *(float4*)&zr_s[cc][8 * sq];
            float4 zr1 = *(float4*)&zr_s[cc][8 * sq + 4];
            float4 zi0 = *(float4*)&zi_s[cc][8 * sq];
            float4 zi1 = *(float4*)&zi_s[cc][8 * sq + 4];
            CFMA4(a00, w_r.x, w_i.x, zr0, zi0); CFMA4(a01, w_r.x, w_i.x, zr1, zi1);
            CFMA4(a10, w_r.y, w_i.y, zr0, zi0); CFMA4(a11, w_r.y, w_i.y, zr1, zi1);
            CFMA4(a20, w_r.z, w_i.z, zr0, zi0); CFMA4(a21, w_r.z, w_i.z, zr1, zi1);
            CFMA4(a30, w_r.w, w_i.w, zr0, zi0); CFMA4(a31, w_r.w, w_i.w, zr1, zi1);
        }
    }
    size_t obase = (size_t)(b * 128 + 4 * dq) * 16384 + x * 128 + 8 * sq;
    *(float4*)(zre + obase) = a00;
    *(float4*)(zre + obase + 4) = a01;
    *(float4*)(zre + obase + 16384) = a10;
    *(float4*)(zre + obase + 16384 + 4) = a11;
    *(float4*)(zre + obase + 32768) = a20;
    *(float4*)(zre + obase + 32768 + 4) = a21;
    *(float4*)(zre + obase + 49152) = a30;
    *(float4*)(zre + obase + 49152 + 4) = a31;
}

extern "C" void kernel_launch(void* const* d_in, const int* in_sizes, int n_in,
                              void* d_out, int out_size, void* d_ws, size_t ws_size,
                              hipStream_t stream) {
    const float* u_re  = (const float*)d_in[0];
    const float* u_im  = (const float*)d_in[1];
    const float* logA  = (const float*)d_in[2];
    const float* Aim   = (const float*)d_in[3];
    const float* Bre   = (const float*)d_in[4];
    const float* Bim   = (const float*)d_in[5];
    const float* Cre   = (const float*)d_in[6];
    const float* Cim   = (const float*)d_in[7];
    const float* logdt = (const float*)d_in[8];
    const float* Wre   = (const float*)d_in[9];
    const float* Wim   = (const float*)d_in[10];
    float* kbuf = (float*)d_ws;                 // 256 KB
    float* wsA  = (float*)d_ws + 65536;         // 33.5 MB: z1_re, then z2_im
    float* outp = (float*)d_out;                // z1_im, then z2_re, then final

    hipLaunchKernelGGL(compute_k_kernel, dim3(128), dim3(256), 0, stream,
                       logA, Aim, Bre, Bim, Cre, Cim, logdt, kbuf);
    hipLaunchKernelGGL(conv_x_kernel, dim3(B_ * C_ * 2), dim3(512), 0, stream,
                       u_re, u_im, kbuf, wsA, outp);
    hipLaunchKernelGGL(conv_y_kernel, dim3(B_ * C_ * 2), dim3(512), 0, stream,
                       wsA, outp, kbuf);
    hipLaunchKernelGGL(mix_kernel, dim3(B_ * 128), dim3(512), 0, stream,
                       outp, wsA, Wre, Wim);
}

// Round 7
// 447.943 us; speedup vs baseline: 4.6446x; 4.6446x over previous
//
#include <hip/hip_runtime.h>

#define B_ 4
#define C_ 128
#define L_ 128
#define N_ 64

__device__ __forceinline__ float fget(const float4& v, int e) {
    switch (e) { case 0: return v.x; case 1: return v.y; case 2: return v.z; default: return v.w; }
}

__device__ __forceinline__ void cfma(float4& ar, float4& ai, float kr, float ki,
                                     const float4& vr, const float4& vi) {
    ar.x += kr * vr.x - ki * vi.x; ai.x += kr * vi.x + ki * vr.x;
    ar.y += kr * vr.y - ki * vi.y; ai.y += kr * vi.y + ki * vr.y;
    ar.z += kr * vr.z - ki * vi.z; ai.z += kr * vi.z + ki * vr.z;
    ar.w += kr * vr.w - ki * vi.w; ai.w += kr * vi.w + ki * vr.w;
}

// real-part complex FMA: acc += wr*zr - wi*zi (componentwise on float4)
#define CFMA4(acc, wr_, wi_, zr_, zi_)                                     \
    acc.x += (wr_) * (zr_).x - (wi_) * (zi_).x;                            \
    acc.y += (wr_) * (zr_).y - (wi_) * (zi_).y;                            \
    acc.z += (wr_) * (zr_).z - (wi_) * (zi_).z;                            \
    acc.w += (wr_) * (zr_).w - (wi_) * (zi_).w;

// ---------------- Kernel A: SSM kernels k0,k1 ----------------
// kbuf floats: [k0_re 16384][k0_im 16384][k1_re 16384][k1_im 16384]
__global__ __launch_bounds__(256) void compute_k_kernel(
    const float* __restrict__ logA, const float* __restrict__ Aim,
    const float* __restrict__ Bre, const float* __restrict__ Bim,
    const float* __restrict__ Cre, const float* __restrict__ Cim,
    const float* __restrict__ logdt, float* __restrict__ kbuf)
{
    int idx = blockIdx.x * 256 + threadIdx.x;   // axis*16384 + c*128 + t
    int axis = idx >> 14;
    int c = (idx >> 7) & 127;
    int t = idx & 127;
    float dt = expf(logdt[axis * C_ + c]);
    float tf = (float)t;
    const float* lA = logA + (axis * C_ + c) * N_;
    const float* br = Bre + (axis * C_ + c) * N_;
    const float* bi = Bim + (axis * C_ + c) * N_;
    const float* cr = Cre + (axis * C_ + c) * N_;
    const float* ci = Cim + (axis * C_ + c) * N_;
    const float* ai = Aim + axis * N_;
    float kr = 0.f, ki = 0.f;
    for (int n = 0; n < N_; ++n) {
        float zre = -expf(lA[n]) * dt;
        float zim = ai[n] * dt;
        float mag = expf(zre * tf);
        float s, co;
        sincosf(zim * tf, &s, &co);
        float wr = mag * co, wi = mag * s;
        float cbr = cr[n] * br[n] - ci[n] * bi[n];
        float cbi = cr[n] * bi[n] + ci[n] * br[n];
        kr += cbr * wr - cbi * wi;
        ki += cbr * wi + cbi * wr;
    }
    kbuf[axis * 32768 + c * L_ + t] = kr;
    kbuf[axis * 32768 + 16384 + c * L_ + t] = ki;
}

// ---------------- conv_x: z1(x,y) = sum_{a<=x} k0[x-a]*u(a,y) ----------------
__global__ __launch_bounds__(512) void conv_x_kernel(
    const float* __restrict__ u_re, const float* __restrict__ u_im,
    const float* __restrict__ kbuf, float* __restrict__ z_re, float* __restrict__ z_im)
{
    __shared__ float sre[128 * 64];
    __shared__ float sim[128 * 64];
    __shared__ float ktr[136], kti[136];
    int blk = blockIdx.x;
    int half = blk & 1;
    int c = (blk >> 1) & 127;
    int b = blk >> 8;
    int tid = threadIdx.x;
    if (tid < 136) {
        int t = tid - 7;
        bool v = (t >= 0) && (t < 128);
        ktr[tid] = v ? kbuf[c * 128 + t] : 0.f;
        kti[tid] = v ? kbuf[16384 + c * 128 + t] : 0.f;
    }
    size_t base = (size_t)(b * 128 + c) * 16384;
#pragma unroll
    for (int it = 0; it < 4; ++it) {
        int i4 = it * 512 + tid;
        int r = i4 >> 4, c4 = i4 & 15;
        float4 vr = *(const float4*)(u_re + base + r * 128 + half * 64 + 4 * c4);
        float4 vi = *(const float4*)(u_im + base + r * 128 + half * 64 + 4 * c4);
        int p = r * 64 + 4 * (c4 ^ (r & 15));
        *(float4*)&sre[p] = vr;
        *(float4*)&sim[p] = vi;
    }
    __syncthreads();
    int w = tid >> 6;
    int wb = half ? (7 - w) : w;            // parity flip: co-resident blocks complement
    int lane = tid & 63;
    int rq = 4 * wb + ((lane >> 4) & 3);    // output x-block 0..31
    int cq = lane & 15;                     // y float4-col
    int r0 = 4 * rq;
    int abound = 16 * wb + 15;              // wave-uniform triangular bound
    float4 accr[4], acci[4];
#pragma unroll
    for (int k = 0; k < 4; ++k) {
        accr[k] = make_float4(0.f, 0.f, 0.f, 0.f);
        acci[k] = make_float4(0.f, 0.f, 0.f, 0.f);
    }
    for (int a = 0; a <= abound; ++a) {
        int p = a * 64 + 4 * (cq ^ (a & 15));
        float4 vr = *(const float4*)&sre[p];
        float4 vi = *(const float4*)&sim[p];
        int jb = r0 - a + 7;
#pragma unroll
        for (int k = 0; k < 4; ++k) {
            int j = jb + k; j = j < 0 ? 0 : j;
            cfma(accr[k], acci[k], ktr[j], kti[j], vr, vi);
        }
    }
#pragma unroll
    for (int k = 0; k < 4; ++k) {
        *(float4*)(z_re + base + (size_t)(r0 + k) * 128 + half * 64 + 4 * cq) = accr[k];
        *(float4*)(z_im + base + (size_t)(r0 + k) * 128 + half * 64 + 4 * cq) = acci[k];
    }
}

// ---------------- conv_y: z2(x,y) = sum_{j<=y} k1[y-j]*z1(x,j) ----------------
__global__ __launch_bounds__(512) void conv_y_kernel(
    float* __restrict__ z_re /* ws: z1_re in, z2_im out */,
    float* __restrict__ z_im /* d_out: z1_im in, z2_re out */,
    const float* __restrict__ kbuf)
{
    __shared__ float sre[128 * 64];
    __shared__ float sim[128 * 64];
    __shared__ float ktr[136], kti[136];
    int blk = blockIdx.x;
    int half = blk & 1;
    int c = (blk >> 1) & 127;
    int b = blk >> 8;
    int tid = threadIdx.x;
    if (tid < 136) {
        int t = tid - 7;
        bool v = (t >= 0) && (t < 128);
        ktr[tid] = v ? kbuf[32768 + c * 128 + t] : 0.f;
        kti[tid] = v ? kbuf[49152 + c * 128 + t] : 0.f;
    }
    size_t base = (size_t)(b * 128 + c) * 16384;
#pragma unroll
    for (int it = 0; it < 4; ++it) {
        int i4 = it * 512 + tid;
        int xl = i4 >> 5, q = i4 & 31;
        float4 vr = *(const float4*)(z_re + base + (size_t)(half * 64 + xl) * 128 + 4 * q);
        float4 vi = *(const float4*)(z_im + base + (size_t)(half * 64 + xl) * 128 + 4 * q);
        int c4 = xl >> 2, e0 = xl & 3;
#pragma unroll
        for (int e = 0; e < 4; ++e) {
            int y = 4 * q + e;
            int p = y * 64 + 4 * (c4 ^ (y & 15)) + e0;
            sre[p] = fget(vr, e);
            sim[p] = fget(vi, e);
        }
    }
    __syncthreads();
    int w = tid >> 6;
    int wb = half ? (7 - w) : w;
    int lane = tid & 63;
    int rq = 4 * wb + ((lane >> 4) & 3);    // output y-block 0..31
    int cq = lane & 15;                     // x float4-col
    int r0 = 4 * rq;
    int abound = 16 * wb + 15;
    float4 accr[4], acci[4];
#pragma unroll
    for (int k = 0; k < 4; ++k) {
        accr[k] = make_float4(0.f, 0.f, 0.f, 0.f);
        acci[k] = make_float4(0.f, 0.f, 0.f, 0.f);
    }
    for (int a = 0; a <= abound; ++a) {      // a = j
        int p = a * 64 + 4 * (cq ^ (a & 15));
        float4 vr = *(const float4*)&sre[p];
        float4 vi = *(const float4*)&sim[p];
        int jb = r0 - a + 7;
#pragma unroll
        for (int k = 0; k < 4; ++k) {
            int j = jb + k; j = j < 0 ? 0 : j;
            cfma(accr[k], acci[k], ktr[j], kti[j], vr, vi);
        }
    }
    __syncthreads();
#pragma unroll
    for (int e = 0; e < 4; ++e) {
        int cc = 4 * cq + e;
        int p = cc * 128 + 4 * (rq ^ (cc >> 2));
        *(float4*)&sre[p] = make_float4(fget(accr[0], e), fget(accr[1], e), fget(accr[2], e), fget(accr[3], e));
        *(float4*)&sim[p] = make_float4(fget(acci[0], e), fget(acci[1], e), fget(acci[2], e), fget(acci[3], e));
    }
    __syncthreads();
    int cc = tid >> 3, fq = tid & 7;
#pragma unroll
    for (int mm = 0; mm < 4; ++mm) {
        int o4 = fq + 8 * mm;
        int p = cc * 128 + 4 * (o4 ^ (cc >> 2));
        float4 vre = *(float4*)&sre[p];   // z2_re
        float4 vim = *(float4*)&sim[p];   // z2_im
        *(float4*)(z_im + base + (size_t)(half * 64 + cc) * 128 + 4 * o4) = vre;  // -> d_out
        *(float4*)(z_re + base + (size_t)(half * 64 + cc) * 128 + 4 * o4) = vim;  // -> ws
    }
}

// ---------------- mix v7: out[b,d,s] = sum_c Wre[d,c]*zre[b,c,s] - Wim[d,c]*zim[b,c,s] ----------------
// 256 threads, grid 1024 (4b x 256 s-tiles of 64). Block covers ALL 128 d (in-place safe).
// Per thread 8d x 4s, 8 NAMED float4 accs. No launch_bounds cap -> no spill.
__global__ __launch_bounds__(256) void mix_kernel(
    float* __restrict__ zre /* d_out */, const float* __restrict__ zim /* ws */,
    const float* __restrict__ Wre, const float* __restrict__ Wim)
{
    __shared__ float zr_s[16][68];
    __shared__ float zi_s[16][68];
    __shared__ float wr_s[16][132];
    __shared__ float wi_s[16][132];
    int bid = blockIdx.x;          // b*256 + stile
    int b = bid >> 8;
    int s0 = (bid & 255) << 6;
    int tid = threadIdx.x;
    int sq = tid & 15;             // s: 4sq..4sq+3
    int dq = tid >> 4;             // d: 8dq..8dq+7
    float4 a0 = {0,0,0,0}, a1 = {0,0,0,0}, a2 = {0,0,0,0}, a3 = {0,0,0,0};
    float4 a4 = {0,0,0,0}, a5 = {0,0,0,0}, a6 = {0,0,0,0}, a7 = {0,0,0,0};

    for (int c0 = 0; c0 < 128; c0 += 16) {
        __syncthreads();
        {   // z stage: 16c x 16 s-quads -> 1 float4/thread/array
            int cc = tid >> 4, q = tid & 15;
            size_t g = (size_t)(b * 128 + c0 + cc) * 16384 + s0 + 4 * q;
            *(float4*)&zr_s[cc][4 * q] = *(const float4*)(zre + g);
            *(float4*)&zi_s[cc][4 * q] = *(const float4*)(zim + g);
        }
        {   // W stage transposed: thread (dW=tid>>1, half qb) loads 8 c each
            int dW = tid >> 1;
            int qb = (tid & 1) * 8;
            float4 wr0 = *(const float4*)&Wre[dW * 128 + c0 + qb];
            float4 wr1 = *(const float4*)&Wre[dW * 128 + c0 + qb + 4];
            float4 wi0 = *(const float4*)&Wim[dW * 128 + c0 + qb];
            float4 wi1 = *(const float4*)&Wim[dW * 128 + c0 + qb + 4];
            wr_s[qb + 0][dW] = wr0.x; wr_s[qb + 1][dW] = wr0.y;
            wr_s[qb + 2][dW] = wr0.z; wr_s[qb + 3][dW] = wr0.w;
            wr_s[qb + 4][dW] = wr1.x; wr_s[qb + 5][dW] = wr1.y;
            wr_s[qb + 6][dW] = wr1.z; wr_s[qb + 7][dW] = wr1.w;
            wi_s[qb + 0][dW] = wi0.x; wi_s[qb + 1][dW] = wi0.y;
            wi_s[qb + 2][dW] = wi0.z; wi_s[qb + 3][dW] = wi0.w;
            wi_s[qb + 4][dW] = wi1.x; wi_s[qb + 5][dW] = wi1.y;
            wi_s[qb + 6][dW] = wi1.z; wi_s[qb + 7][dW] = wi1.w;
        }
        __syncthreads();
#pragma unroll
        for (int cc = 0; cc < 16; ++cc) {
            float4 zr = *(float4*)&zr_s[cc][4 * sq];
            float4 zi = *(float4*)&zi_s[cc][4 * sq];
            float4 wr0 = *(float4*)&wr_s[cc][8 * dq];
            float4 wr1 = *(float4*)&wr_s[cc][8 * dq + 4];
            float4 wi0 = *(float4*)&wi_s[cc][8 * dq];
            float4 wi1 = *(float4*)&wi_s[cc][8 * dq + 4];
            CFMA4(a0, wr0.x, wi0.x, zr, zi);
            CFMA4(a1, wr0.y, wi0.y, zr, zi);
            CFMA4(a2, wr0.z, wi0.z, zr, zi);
            CFMA4(a3, wr0.w, wi0.w, zr, zi);
            CFMA4(a4, wr1.x, wi1.x, zr, zi);
            CFMA4(a5, wr1.y, wi1.y, zr, zi);
            CFMA4(a6, wr1.z, wi1.z, zr, zi);
            CFMA4(a7, wr1.w, wi1.w, zr, zi);
        }
    }
    size_t ob = (size_t)(b * 128 + 8 * dq) * 16384 + s0 + 4 * sq;
    *(float4*)(zre + ob) = a0;
    *(float4*)(zre + ob + 1 * 16384) = a1;
    *(float4*)(zre + ob + 2 * 16384) = a2;
    *(float4*)(zre + ob + 3 * 16384) = a3;
    *(float4*)(zre + ob + 4 * 16384) = a4;
    *(float4*)(zre + ob + 5 * 16384) = a5;
    *(float4*)(zre + ob + 6 * 16384) = a6;
    *(float4*)(zre + ob + 7 * 16384) = a7;
}

extern "C" void kernel_launch(void* const* d_in, const int* in_sizes, int n_in,
                              void* d_out, int out_size, void* d_ws, size_t ws_size,
                              hipStream_t stream) {
    const float* u_re  = (const float*)d_in[0];
    const float* u_im  = (const float*)d_in[1];
    const float* logA  = (const float*)d_in[2];
    const float* Aim   = (const float*)d_in[3];
    const float* Bre   = (const float*)d_in[4];
    const float* Bim   = (const float*)d_in[5];
    const float* Cre   = (const float*)d_in[6];
    const float* Cim   = (const float*)d_in[7];
    const float* logdt = (const float*)d_in[8];
    const float* Wre   = (const float*)d_in[9];
    const float* Wim   = (const float*)d_in[10];
    float* kbuf = (float*)d_ws;                 // 256 KB
    float* wsA  = (float*)d_ws + 65536;         // 33.5 MB: z1_re, then z2_im
    float* outp = (float*)d_out;                // z1_im, then z2_re, then final

    hipLaunchKernelGGL(compute_k_kernel, dim3(128), dim3(256), 0, stream,
                       logA, Aim, Bre, Bim, Cre, Cim, logdt, kbuf);
    hipLaunchKernelGGL(conv_x_kernel, dim3(B_ * C_ * 2), dim3(512), 0, stream,
                       u_re, u_im, kbuf, wsA, outp);
    hipLaunchKernelGGL(conv_y_kernel, dim3(B_ * C_ * 2), dim3(512), 0, stream,
                       wsA, outp, kbuf);
    hipLaunchKernelGGL(mix_kernel, dim3(B_ * 256), dim3(256), 0, stream,
                       outp, wsA, Wre, Wim);
}